// Round 6
// baseline (326.928 us; speedup 1.0000x reference)
//
#include <hip/hip_runtime.h>
#include <stdint.h>

typedef short short8 __attribute__((ext_vector_type(8)));
typedef float f32x4 __attribute__((ext_vector_type(4)));

#define LOG2E 1.44269504088896f
#define AS1 __attribute__((address_space(1)))
#define AS3 __attribute__((address_space(3)))

__device__ __forceinline__ float fexp2(float x) {
#if __has_builtin(__builtin_amdgcn_exp2f)
    return __builtin_amdgcn_exp2f(x);   // bare v_exp_f32
#else
    return exp2f(x);
#endif
}
__device__ __forceinline__ unsigned short f2bfbits(float f) {
    unsigned x = __builtin_bit_cast(unsigned, f);
    unsigned r = x + 0x7fffu + ((x >> 16) & 1u);
    return (unsigned short)(r >> 16);
}
__device__ __forceinline__ float bfbits2f(unsigned short b) {
    unsigned u = ((unsigned)b) << 16;
    return __builtin_bit_cast(float, u);
}
__device__ __forceinline__ void unpack8(uint4 u, float4& f0, float4& f1) {
    f0.x = bfbits2f((unsigned short)(u.x & 0xffffu)); f0.y = bfbits2f((unsigned short)(u.x >> 16));
    f0.z = bfbits2f((unsigned short)(u.y & 0xffffu)); f0.w = bfbits2f((unsigned short)(u.y >> 16));
    f1.x = bfbits2f((unsigned short)(u.z & 0xffffu)); f1.y = bfbits2f((unsigned short)(u.z >> 16));
    f1.z = bfbits2f((unsigned short)(u.w & 0xffffu)); f1.w = bfbits2f((unsigned short)(u.w >> 16));
}
__device__ __forceinline__ unsigned pack2(float a, float b) {
    return (unsigned)f2bfbits(a) | ((unsigned)f2bfbits(b) << 16);
}
// truncate-pack two positive fp32 to bf16x2 (3 ops; consistent w/ l via MFMA)
__device__ __forceinline__ unsigned tpack2(float a, float b) {
    return (__builtin_bit_cast(unsigned, a) >> 16) | (__builtin_bit_cast(unsigned, b) & 0xffff0000u);
}
// async 16B/lane global->LDS; lp wave-uniform base, lanes scatter +lane*16
__device__ __forceinline__ void glds16(const void* gp, void* lp) {
    __builtin_amdgcn_global_load_lds((const AS1 unsigned*)(uintptr_t)gp,
                                     (AS3 unsigned*)(unsigned)(uintptr_t)lp, 16, 0, 0);
}

// ------- flat fp32 -> bf16 convert (RNE) -------
__global__ __launch_bounds__(256) void xbf_k(const float* __restrict__ x,
                                             unsigned short* __restrict__ y) {
    int i = (blockIdx.x * 256 + threadIdx.x) * 4;
    float4 v = *(const float4*)(x + i);
    uint2 u;
    u.x = pack2(v.x, v.y);
    u.y = pack2(v.z, v.w);
    *(uint2*)(y + i) = u;
}

// ------- transpose + fp32->bf16 convert: src[R][C] fp32 -> dst[C][R] bf16 -------
__global__ __launch_bounds__(256) void t32cvt_k(const float* __restrict__ src,
                                                unsigned short* __restrict__ dst,
                                                int R, int C) {
    __shared__ float tile[32][36];
    int t = threadIdx.x;
    int bx = blockIdx.x, by = blockIdx.y;
    int r = t >> 3, c0 = (t & 7) * 4;
    *(float4*)&tile[r][c0] = *(const float4*)(src + (size_t)(by * 32 + r) * C + bx * 32 + c0);
    __syncthreads();
    uint2 u;
    u.x = pack2(tile[c0 + 0][r], tile[c0 + 1][r]);
    u.y = pack2(tile[c0 + 2][r], tile[c0 + 3][r]);
    *(uint2*)(dst + (size_t)(bx * 32 + r) * R + by * 32 + c0) = u;
}

// ---- GEMM (m97-style): C[M,N] = A[M,K] bf16 * Bt[N,K]^T bf16 ; C fp32 or bf16 ----
template <bool CF32>
__global__ __launch_bounds__(256) void gemm_k(const unsigned short* __restrict__ A,
                                              const unsigned short* __restrict__ Bt,
                                              void* __restrict__ Cv,
                                              int M, int N, int K) {
    __shared__ unsigned short sA[128 * 32];   // unpadded (global_load_lds lane-scatter)
    __shared__ unsigned short sB[128 * 32];
    int t = threadIdx.x;
    int wid = t >> 6, lane = t & 63;
    int wm = (wid >> 1) * 64, wn = (wid & 1) * 64;
    int lm = lane & 15, lq = lane >> 4;
    size_t m0 = (size_t)blockIdx.y * 128, n0 = (size_t)blockIdx.x * 128;
    int srow = t >> 2, scol = (t & 3) * 8;
    const unsigned short* ga0 = A + (m0 + srow) * K + scol;
    const unsigned short* ga1 = A + (m0 + 64 + srow) * K + scol;
    const unsigned short* gb0 = Bt + (n0 + srow) * K + scol;
    const unsigned short* gb1 = Bt + (n0 + 64 + srow) * K + scol;
    unsigned short* laA0 = &sA[wid * 512];
    unsigned short* laA1 = &sA[2048 + wid * 512];
    unsigned short* laB0 = &sB[wid * 512];
    unsigned short* laB1 = &sB[2048 + wid * 512];
    f32x4 acc[4][4] = {};
    for (int k0 = 0; k0 < K; k0 += 32) {
        __syncthreads();
        glds16(ga0 + k0, laA0);
        glds16(ga1 + k0, laA1);
        glds16(gb0 + k0, laB0);
        glds16(gb1 + k0, laB1);
        __syncthreads();
        short8 af[4], bfr[4];
        #pragma unroll
        for (int i = 0; i < 4; ++i) af[i] = *(const short8*)&sA[(wm + i * 16 + lm) * 32 + lq * 8];
        #pragma unroll
        for (int j = 0; j < 4; ++j) bfr[j] = *(const short8*)&sB[(wn + j * 16 + lm) * 32 + lq * 8];
        #pragma unroll
        for (int i = 0; i < 4; ++i)
            #pragma unroll
            for (int j = 0; j < 4; ++j)
                acc[i][j] = __builtin_amdgcn_mfma_f32_16x16x32_bf16(af[i], bfr[j], acc[i][j], 0, 0, 0);
    }
    #pragma unroll
    for (int i = 0; i < 4; ++i)
        #pragma unroll
        for (int j = 0; j < 4; ++j)
            #pragma unroll
            for (int r = 0; r < 4; ++r) {
                size_t row = m0 + wm + i * 16 + lq * 4 + r;
                size_t col = n0 + wn + j * 16 + lm;
                if (CF32) ((float*)Cv)[row * N + col] = acc[i][j][r];
                else ((unsigned short*)Cv)[row * N + col] = f2bfbits(acc[i][j][r]);
            }
}

// ------- V transpose: per (b,h): V[2048 k][64 d] -> Vt[64 d][2048 k], bf16 -------
__global__ __launch_bounds__(256) void vt_k(const unsigned short* __restrict__ qkv,
                                            unsigned short* __restrict__ vt) {
    __shared__ unsigned short tile[64 * 72];
    int kt = blockIdx.x, bh = blockIdx.y;
    int b = bh >> 4, h = bh & 15;
    const unsigned short* Vp = qkv + (size_t)b * 6291456 + 4194304 + (size_t)h * 131072;
    int t = threadIdx.x;
    int row = t >> 2, cc = (t & 3) * 16;
    const unsigned short* src = Vp + (size_t)(kt * 64 + row) * 64 + cc;
    *(uint4*)&tile[row * 72 + cc] = *(const uint4*)src;
    *(uint4*)&tile[row * 72 + cc + 8] = *(const uint4*)(src + 8);
    __syncthreads();
    unsigned v[8];
    #pragma unroll
    for (int j = 0; j < 8; ++j) {
        unsigned short a = tile[(cc + 2 * j) * 72 + row];
        unsigned short bsh = tile[(cc + 2 * j + 1) * 72 + row];
        v[j] = (unsigned)a | ((unsigned)bsh << 16);
    }
    unsigned short* dst = vt + ((size_t)bh * 64 + row) * 2048 + kt * 64 + cc;
    *(uint4*)dst = make_uint4(v[0], v[1], v[2], v[3]);
    *(uint4*)(dst + 8) = make_uint4(v[4], v[5], v[6], v[7]);
}

// ------- MFMA flash attention (S^T form): block = (b,h, 256q); 4 waves x 64 q -------
// S^T = K·Q^T (operand swap, same frags); P^T packed b64 into wave-private PsT[q][k];
// O^T = V^T·P^T; l via ones-MFMA. 2 barriers/kt (PsT needs no barrier).
__global__ __launch_bounds__(256, 2) void attn_mfma(const unsigned short* __restrict__ qkv,
                                                    const unsigned short* __restrict__ vt,
                                                    unsigned short* __restrict__ aout) {
    __shared__ unsigned short Ks[64 * 72];     // [k 64][d 64] pad 72
    __shared__ unsigned short Vs[64 * 72];     // [d 64][k 64] pad 72
    __shared__ unsigned short Ps[4 * 64 * 68]; // per wave [q 64][k 64] pad 68
    int bid = blockIdx.x;
    int qt = bid & 7, h = (bid >> 3) & 15, b = bid >> 7;
    int t = threadIdx.x;
    int wave = t >> 6, lane = t & 63, lm = lane & 15, quad = lane >> 4;
    const unsigned short* Qb = qkv + (size_t)b * 6291456 + (size_t)h * 131072;
    const unsigned short* Kb = Qb + 2097152;
    const unsigned short* Vtb = vt + (size_t)(b * 16 + h) * 131072;  // [64][2048]
    int q0 = qt * 256 + wave * 64;

    // persistent Q fragments, pre-scaled by 0.125*log2(e); serve as B-operand (Q^T)
    const float qs = 0.125f * LOG2E;
    short8 qf[4][2];
    #pragma unroll
    for (int i = 0; i < 4; ++i)
        #pragma unroll
        for (int c = 0; c < 2; ++c) {
            uint4 u = *(const uint4*)(Qb + (size_t)(q0 + i * 16 + lm) * 64 + c * 32 + quad * 8);
            float4 f0, f1; unpack8(u, f0, f1);
            uint4 v;
            v.x = pack2(f0.x * qs, f0.y * qs);
            v.y = pack2(f0.z * qs, f0.w * qs);
            v.z = pack2(f1.x * qs, f1.y * qs);
            v.w = pack2(f1.z * qs, f1.w * qs);
            qf[i][c] = *(short8*)&v;
        }

    short8 ones;
    #pragma unroll
    for (int z = 0; z < 8; ++z) ones[z] = (short)0x3F80;  // bf16 1.0

    f32x4 o[4][4] = {};    // o[jd][i] = O^T tile (rows d, cols q)
    f32x4 l_acc[4] = {};

    int srow = t >> 2, scol = (t & 3) * 16;
    unsigned short* psw = Ps + wave * 4352;   // 64*68

    for (int kt = 0; kt < 32; ++kt) {
        const unsigned short* kp = Kb + (size_t)(kt * 64 + srow) * 64 + scol;
        uint4 k0 = *(const uint4*)kp;
        uint4 k1 = *(const uint4*)(kp + 8);
        const unsigned short* vp = Vtb + (size_t)srow * 2048 + kt * 64 + scol;
        uint4 v0 = *(const uint4*)vp;
        uint4 v1 = *(const uint4*)(vp + 8);
        __syncthreads();   // all waves done reading Ks/Vs of prev kt
        *(uint4*)&Ks[srow * 72 + scol] = k0;
        *(uint4*)&Ks[srow * 72 + scol + 8] = k1;
        *(uint4*)&Vs[srow * 72 + scol] = v0;
        *(uint4*)&Vs[srow * 72 + scol + 8] = v1;
        __syncthreads();   // staged

        // S^T = K Q^T : tile (j = k-16, i = q-16); C-layout row=k(quad*4+r), col=q(lm)
        #pragma unroll
        for (int j = 0; j < 4; ++j) {
            short8 kf0 = *(const short8*)&Ks[(j * 16 + lm) * 72 + quad * 8];
            short8 kf1 = *(const short8*)&Ks[(j * 16 + lm) * 72 + 32 + quad * 8];
            #pragma unroll
            for (int i = 0; i < 4; ++i) {
                f32x4 sf = {0.f, 0.f, 0.f, 0.f};
                sf = __builtin_amdgcn_mfma_f32_16x16x32_bf16(kf0, qf[i][0], sf, 0, 0, 0);
                sf = __builtin_amdgcn_mfma_f32_16x16x32_bf16(kf1, qf[i][1], sf, 0, 0, 0);
                // p = 2^sf, 4 consecutive k for q=lm -> one b64 packed write
                float p0 = fexp2(sf[0]), p1 = fexp2(sf[1]);
                float p2 = fexp2(sf[2]), p3 = fexp2(sf[3]);
                uint2 w;
                w.x = tpack2(p0, p1);
                w.y = tpack2(p2, p3);
                *(uint2*)&psw[(i * 16 + lm) * 68 + j * 16 + quad * 4] = w;
            }
        }
        // no barrier: PsT is wave-private (in-wave lgkmcnt orders write->read)

        // O^T += V^T P^T ; l += ones·P^T
        #pragma unroll
        for (int c = 0; c < 2; ++c) {
            short8 pf[4];
            #pragma unroll
            for (int i = 0; i < 4; ++i)
                pf[i] = *(const short8*)&psw[(i * 16 + lm) * 68 + c * 32 + quad * 8];
            #pragma unroll
            for (int jd = 0; jd < 4; ++jd) {
                short8 vf = *(const short8*)&Vs[(jd * 16 + lm) * 72 + c * 32 + quad * 8];
                #pragma unroll
                for (int i = 0; i < 4; ++i)
                    o[jd][i] = __builtin_amdgcn_mfma_f32_16x16x32_bf16(vf, pf[i], o[jd][i], 0, 0, 0);
            }
            #pragma unroll
            for (int i = 0; i < 4; ++i)
                l_acc[i] = __builtin_amdgcn_mfma_f32_16x16x32_bf16(ones, pf[i], l_acc[i], 0, 0, 0);
        }
    }
    // epilogue: lane holds O[q = q0+i*16+lm][d = jd*16+quad*4+r]; b64 packed stores
    #pragma unroll
    for (int i = 0; i < 4; ++i) {
        float inv = 1.f / l_acc[i][0];   // all rows of ones-MFMA equal l[q=lm]
        size_t row = (size_t)b * 2048 + q0 + i * 16 + lm;
        unsigned short* op = aout + row * 1024 + h * 64 + quad * 4;
        #pragma unroll
        for (int jd = 0; jd < 4; ++jd) {
            uint2 u;
            u.x = pack2(o[jd][i][0] * inv, o[jd][i][1] * inv);
            u.y = pack2(o[jd][i][2] * inv, o[jd][i][3] * inv);
            *(uint2*)(op + jd * 16) = u;
        }
    }
}

extern "C" void kernel_launch(void* const* d_in, const int* in_sizes, int n_in,
                              void* d_out, int out_size, void* d_ws, size_t ws_size,
                              hipStream_t stream) {
    const float* xin  = (const float*)d_in[0];   // [8192,1024] fp32
    const float* wqkv = (const float*)d_in[1];   // [1024,3072] fp32
    const float* wo   = (const float*)d_in[2];   // [1024,1024] fp32
    float* out = (float*)d_out;                  // [8192,1024] fp32

    char* ws = (char*)d_ws;
    unsigned short* qkv   = (unsigned short*)(ws);                 // 50,331,648 B
    unsigned short* attn  = (unsigned short*)(ws + 50331648);      // 16,777,216 B
    unsigned short* wqkvT = (unsigned short*)(ws + 67108864);      //  6,291,456 B
    unsigned short* woT   = (unsigned short*)(ws + 73400320);      //  2,097,152 B
    unsigned short* vt    = (unsigned short*)(ws + 75497472);      // 16,777,216 B
    unsigned short* xb    = (unsigned short*)(ws + 92274688);      // 16,777,216 B

    dim3 blk(256);
    xbf_k<<<dim3(8192), blk, 0, stream>>>(xin, xb);
    t32cvt_k<<<dim3(3072 / 32, 1024 / 32), blk, 0, stream>>>(wqkv, wqkvT, 1024, 3072);
    t32cvt_k<<<dim3(1024 / 32, 1024 / 32), blk, 0, stream>>>(wo, woT, 1024, 1024);
    gemm_k<false><<<dim3(3072 / 128, 8192 / 128), blk, 0, stream>>>(xb, wqkvT, qkv, 8192, 3072, 1024);
    vt_k<<<dim3(32, 64), blk, 0, stream>>>(qkv, vt);
    attn_mfma<<<dim3(512), blk, 0, stream>>>(qkv, vt, attn);
    gemm_k<true><<<dim3(1024 / 128, 8192 / 128), blk, 0, stream>>>(attn, woT, out, 8192, 1024, 1024);
}

// Round 7
// 326.310 us; speedup vs baseline: 1.0019x; 1.0019x over previous
//
#include <hip/hip_runtime.h>
#include <stdint.h>

typedef short short8 __attribute__((ext_vector_type(8)));
typedef float f32x4 __attribute__((ext_vector_type(4)));

#define LOG2E 1.44269504088896f
#define AS1 __attribute__((address_space(1)))
#define AS3 __attribute__((address_space(3)))

__device__ __forceinline__ float fexp2(float x) {
#if __has_builtin(__builtin_amdgcn_exp2f)
    return __builtin_amdgcn_exp2f(x);   // bare v_exp_f32
#else
    return exp2f(x);
#endif
}
__device__ __forceinline__ unsigned short f2bfbits(float f) {
    unsigned x = __builtin_bit_cast(unsigned, f);
    unsigned r = x + 0x7fffu + ((x >> 16) & 1u);
    return (unsigned short)(r >> 16);
}
__device__ __forceinline__ float bfbits2f(unsigned short b) {
    unsigned u = ((unsigned)b) << 16;
    return __builtin_bit_cast(float, u);
}
__device__ __forceinline__ void unpack8(uint4 u, float4& f0, float4& f1) {
    f0.x = bfbits2f((unsigned short)(u.x & 0xffffu)); f0.y = bfbits2f((unsigned short)(u.x >> 16));
    f0.z = bfbits2f((unsigned short)(u.y & 0xffffu)); f0.w = bfbits2f((unsigned short)(u.y >> 16));
    f1.x = bfbits2f((unsigned short)(u.z & 0xffffu)); f1.y = bfbits2f((unsigned short)(u.z >> 16));
    f1.z = bfbits2f((unsigned short)(u.w & 0xffffu)); f1.w = bfbits2f((unsigned short)(u.w >> 16));
}
__device__ __forceinline__ unsigned pack2(float a, float b) {
    return (unsigned)f2bfbits(a) | ((unsigned)f2bfbits(b) << 16);
}
// truncate-pack two positive fp32 to bf16x2 (consistent w/ l via MFMA on same P)
__device__ __forceinline__ unsigned tpack2(float a, float b) {
    return (__builtin_bit_cast(unsigned, a) >> 16) | (__builtin_bit_cast(unsigned, b) & 0xffff0000u);
}
// async 16B/lane global->LDS; lp wave-uniform base, lanes scatter +lane*16
__device__ __forceinline__ void glds16(const void* gp, void* lp) {
    __builtin_amdgcn_global_load_lds((const AS1 unsigned*)(uintptr_t)gp,
                                     (AS3 unsigned*)(unsigned)(uintptr_t)lp, 16, 0, 0);
}

// ------- flat fp32 -> bf16 convert (RNE) -------
__global__ __launch_bounds__(256) void xbf_k(const float* __restrict__ x,
                                             unsigned short* __restrict__ y) {
    int i = (blockIdx.x * 256 + threadIdx.x) * 4;
    float4 v = *(const float4*)(x + i);
    uint2 u;
    u.x = pack2(v.x, v.y);
    u.y = pack2(v.z, v.w);
    *(uint2*)(y + i) = u;
}

// ------- transpose + fp32->bf16 convert: src[R][C] fp32 -> dst[C][R] bf16 -------
__global__ __launch_bounds__(256) void t32cvt_k(const float* __restrict__ src,
                                                unsigned short* __restrict__ dst,
                                                int R, int C) {
    __shared__ float tile[32][36];
    int t = threadIdx.x;
    int bx = blockIdx.x, by = blockIdx.y;
    int r = t >> 3, c0 = (t & 7) * 4;
    *(float4*)&tile[r][c0] = *(const float4*)(src + (size_t)(by * 32 + r) * C + bx * 32 + c0);
    __syncthreads();
    uint2 u;
    u.x = pack2(tile[c0 + 0][r], tile[c0 + 1][r]);
    u.y = pack2(tile[c0 + 2][r], tile[c0 + 3][r]);
    *(uint2*)(dst + (size_t)(bx * 32 + r) * R + by * 32 + c0) = u;
}

// ---- GEMM (m97-style): C[M,N] = A[M,K] bf16 * Bt[N,K]^T bf16 ; C fp32 or bf16 ----
template <bool CF32>
__global__ __launch_bounds__(256) void gemm_k(const unsigned short* __restrict__ A,
                                              const unsigned short* __restrict__ Bt,
                                              void* __restrict__ Cv,
                                              int M, int N, int K) {
    __shared__ unsigned short sA[128 * 32];   // unpadded (global_load_lds lane-scatter)
    __shared__ unsigned short sB[128 * 32];
    int t = threadIdx.x;
    int wid = t >> 6, lane = t & 63;
    int wm = (wid >> 1) * 64, wn = (wid & 1) * 64;
    int lm = lane & 15, lq = lane >> 4;
    size_t m0 = (size_t)blockIdx.y * 128, n0 = (size_t)blockIdx.x * 128;
    int srow = t >> 2, scol = (t & 3) * 8;
    const unsigned short* ga0 = A + (m0 + srow) * K + scol;
    const unsigned short* ga1 = A + (m0 + 64 + srow) * K + scol;
    const unsigned short* gb0 = Bt + (n0 + srow) * K + scol;
    const unsigned short* gb1 = Bt + (n0 + 64 + srow) * K + scol;
    unsigned short* laA0 = &sA[wid * 512];
    unsigned short* laA1 = &sA[2048 + wid * 512];
    unsigned short* laB0 = &sB[wid * 512];
    unsigned short* laB1 = &sB[2048 + wid * 512];
    f32x4 acc[4][4] = {};
    for (int k0 = 0; k0 < K; k0 += 32) {
        __syncthreads();
        glds16(ga0 + k0, laA0);
        glds16(ga1 + k0, laA1);
        glds16(gb0 + k0, laB0);
        glds16(gb1 + k0, laB1);
        __syncthreads();
        short8 af[4], bfr[4];
        #pragma unroll
        for (int i = 0; i < 4; ++i) af[i] = *(const short8*)&sA[(wm + i * 16 + lm) * 32 + lq * 8];
        #pragma unroll
        for (int j = 0; j < 4; ++j) bfr[j] = *(const short8*)&sB[(wn + j * 16 + lm) * 32 + lq * 8];
        #pragma unroll
        for (int i = 0; i < 4; ++i)
            #pragma unroll
            for (int j = 0; j < 4; ++j)
                acc[i][j] = __builtin_amdgcn_mfma_f32_16x16x32_bf16(af[i], bfr[j], acc[i][j], 0, 0, 0);
    }
    #pragma unroll
    for (int i = 0; i < 4; ++i)
        #pragma unroll
        for (int j = 0; j < 4; ++j)
            #pragma unroll
            for (int r = 0; r < 4; ++r) {
                size_t row = m0 + wm + i * 16 + lq * 4 + r;
                size_t col = n0 + wn + j * 16 + lm;
                if (CF32) ((float*)Cv)[row * N + col] = acc[i][j][r];
                else ((unsigned short*)Cv)[row * N + col] = f2bfbits(acc[i][j][r]);
            }
}

// ------- V transpose: per (b,h): V[2048 k][64 d] -> Vt[64 d][2048 k], bf16 -------
__global__ __launch_bounds__(256) void vt_k(const unsigned short* __restrict__ qkv,
                                            unsigned short* __restrict__ vt) {
    __shared__ unsigned short tile[64 * 72];
    int kt = blockIdx.x, bh = blockIdx.y;
    int b = bh >> 4, h = bh & 15;
    const unsigned short* Vp = qkv + (size_t)b * 6291456 + 4194304 + (size_t)h * 131072;
    int t = threadIdx.x;
    int row = t >> 2, cc = (t & 3) * 16;
    const unsigned short* src = Vp + (size_t)(kt * 64 + row) * 64 + cc;
    *(uint4*)&tile[row * 72 + cc] = *(const uint4*)src;
    *(uint4*)&tile[row * 72 + cc + 8] = *(const uint4*)(src + 8);
    __syncthreads();
    unsigned v[8];
    #pragma unroll
    for (int j = 0; j < 8; ++j) {
        unsigned short a = tile[(cc + 2 * j) * 72 + row];
        unsigned short bsh = tile[(cc + 2 * j + 1) * 72 + row];
        v[j] = (unsigned)a | ((unsigned)bsh << 16);
    }
    unsigned short* dst = vt + ((size_t)bh * 64 + row) * 2048 + kt * 64 + cc;
    *(uint4*)dst = make_uint4(v[0], v[1], v[2], v[3]);
    *(uint4*)(dst + 8) = make_uint4(v[4], v[5], v[6], v[7]);
}

// ------- MFMA flash attention (S^T form, phase-separated): block = (b,h,256q) -------
// Phase A (per j): 8 MFMAs into sf[4] (4 indep chains). Phase B: exp+pack+b64 writes.
// Phase C: PV + l. 2 barriers/kt; Ps wave-private.
__global__ __launch_bounds__(256, 2) void attn_mfma(const unsigned short* __restrict__ qkv,
                                                    const unsigned short* __restrict__ vt,
                                                    unsigned short* __restrict__ aout) {
    __shared__ unsigned short Ks[64 * 72];     // [k 64][d 64] pad 72
    __shared__ unsigned short Vs[64 * 72];     // [d 64][k 64] pad 72
    __shared__ unsigned short Ps[4 * 64 * 68]; // per wave [q 64][k 64] pad 68
    int bid = blockIdx.x;
    int qt = bid & 7, h = (bid >> 3) & 15, b = bid >> 7;
    int t = threadIdx.x;
    int wave = t >> 6, lane = t & 63, lm = lane & 15, quad = lane >> 4;
    const unsigned short* Qb = qkv + (size_t)b * 6291456 + (size_t)h * 131072;
    const unsigned short* Kb = Qb + 2097152;
    const unsigned short* Vtb = vt + (size_t)(b * 16 + h) * 131072;  // [64][2048]
    int q0 = qt * 256 + wave * 64;

    // persistent Q fragments, pre-scaled by 0.125*log2(e); used as B-operand (Q^T)
    const float qs = 0.125f * LOG2E;
    short8 qf[4][2];
    #pragma unroll
    for (int i = 0; i < 4; ++i)
        #pragma unroll
        for (int c = 0; c < 2; ++c) {
            uint4 u = *(const uint4*)(Qb + (size_t)(q0 + i * 16 + lm) * 64 + c * 32 + quad * 8);
            float4 f0, f1; unpack8(u, f0, f1);
            uint4 v;
            v.x = pack2(f0.x * qs, f0.y * qs);
            v.y = pack2(f0.z * qs, f0.w * qs);
            v.z = pack2(f1.x * qs, f1.y * qs);
            v.w = pack2(f1.z * qs, f1.w * qs);
            qf[i][c] = *(short8*)&v;
        }

    short8 ones;
    #pragma unroll
    for (int z = 0; z < 8; ++z) ones[z] = (short)0x3F80;  // bf16 1.0

    f32x4 o[4][4] = {};    // o[jd][i] = O^T tile (rows d, cols q)
    f32x4 l_acc[4] = {};

    int srow = t >> 2, scol = (t & 3) * 16;
    unsigned short* psw = Ps + wave * 4352;   // 64*68

    for (int kt = 0; kt < 32; ++kt) {
        const unsigned short* kp = Kb + (size_t)(kt * 64 + srow) * 64 + scol;
        uint4 k0 = *(const uint4*)kp;
        uint4 k1 = *(const uint4*)(kp + 8);
        const unsigned short* vp = Vtb + (size_t)srow * 2048 + kt * 64 + scol;
        uint4 v0 = *(const uint4*)vp;
        uint4 v1 = *(const uint4*)(vp + 8);
        __syncthreads();   // all waves done reading Ks/Vs of prev kt
        *(uint4*)&Ks[srow * 72 + scol] = k0;
        *(uint4*)&Ks[srow * 72 + scol + 8] = k1;
        *(uint4*)&Vs[srow * 72 + scol] = v0;
        *(uint4*)&Vs[srow * 72 + scol + 8] = v1;
        __syncthreads();   // staged

        // S^T = K Q^T per j-tile: phase A = 8 MFMAs (4 indep chains), phase B = exp/pack/write
        #pragma unroll
        for (int j = 0; j < 4; ++j) {
            short8 kf0 = *(const short8*)&Ks[(j * 16 + lm) * 72 + quad * 8];
            short8 kf1 = *(const short8*)&Ks[(j * 16 + lm) * 72 + 32 + quad * 8];
            f32x4 sf[4];
            #pragma unroll
            for (int i = 0; i < 4; ++i) {
                sf[i] = (f32x4){0.f, 0.f, 0.f, 0.f};
                sf[i] = __builtin_amdgcn_mfma_f32_16x16x32_bf16(kf0, qf[i][0], sf[i], 0, 0, 0);
                sf[i] = __builtin_amdgcn_mfma_f32_16x16x32_bf16(kf1, qf[i][1], sf[i], 0, 0, 0);
            }
            #pragma unroll
            for (int i = 0; i < 4; ++i) {
                float p0 = fexp2(sf[i][0]), p1 = fexp2(sf[i][1]);
                float p2 = fexp2(sf[i][2]), p3 = fexp2(sf[i][3]);
                uint2 w;
                w.x = tpack2(p0, p1);
                w.y = tpack2(p2, p3);
                *(uint2*)&psw[(i * 16 + lm) * 68 + j * 16 + quad * 4] = w;
            }
        }
        // no barrier: Ps is wave-private (in-wave lgkmcnt orders write->read)

        // O^T += V^T P^T ; l += ones·P^T
        #pragma unroll
        for (int c = 0; c < 2; ++c) {
            short8 pf[4];
            #pragma unroll
            for (int i = 0; i < 4; ++i)
                pf[i] = *(const short8*)&psw[(i * 16 + lm) * 68 + c * 32 + quad * 8];
            #pragma unroll
            for (int jd = 0; jd < 4; ++jd) {
                short8 vf = *(const short8*)&Vs[(jd * 16 + lm) * 72 + c * 32 + quad * 8];
                #pragma unroll
                for (int i = 0; i < 4; ++i)
                    o[jd][i] = __builtin_amdgcn_mfma_f32_16x16x32_bf16(vf, pf[i], o[jd][i], 0, 0, 0);
            }
            #pragma unroll
            for (int i = 0; i < 4; ++i)
                l_acc[i] = __builtin_amdgcn_mfma_f32_16x16x32_bf16(ones, pf[i], l_acc[i], 0, 0, 0);
        }
    }
    // epilogue: lane holds O[q = q0+i*16+lm][d = jd*16+quad*4+r]; b64 packed stores
    #pragma unroll
    for (int i = 0; i < 4; ++i) {
        float inv = 1.f / l_acc[i][0];   // all rows of ones-MFMA equal l[q=lm]
        size_t row = (size_t)b * 2048 + q0 + i * 16 + lm;
        unsigned short* op = aout + row * 1024 + h * 64 + quad * 4;
        #pragma unroll
        for (int jd = 0; jd < 4; ++jd) {
            uint2 u;
            u.x = pack2(o[jd][i][0] * inv, o[jd][i][1] * inv);
            u.y = pack2(o[jd][i][2] * inv, o[jd][i][3] * inv);
            *(uint2*)(op + jd * 16) = u;
        }
    }
}

extern "C" void kernel_launch(void* const* d_in, const int* in_sizes, int n_in,
                              void* d_out, int out_size, void* d_ws, size_t ws_size,
                              hipStream_t stream) {
    const float* xin  = (const float*)d_in[0];   // [8192,1024] fp32
    const float* wqkv = (const float*)d_in[1];   // [1024,3072] fp32
    const float* wo   = (const float*)d_in[2];   // [1024,1024] fp32
    float* out = (float*)d_out;                  // [8192,1024] fp32

    char* ws = (char*)d_ws;
    unsigned short* qkv   = (unsigned short*)(ws);                 // 50,331,648 B
    unsigned short* attn  = (unsigned short*)(ws + 50331648);      // 16,777,216 B
    unsigned short* wqkvT = (unsigned short*)(ws + 67108864);      //  6,291,456 B
    unsigned short* woT   = (unsigned short*)(ws + 73400320);      //  2,097,152 B
    unsigned short* vt    = (unsigned short*)(ws + 75497472);      // 16,777,216 B
    unsigned short* xb    = (unsigned short*)(ws + 92274688);      // 16,777,216 B

    dim3 blk(256);
    xbf_k<<<dim3(8192), blk, 0, stream>>>(xin, xb);
    t32cvt_k<<<dim3(3072 / 32, 1024 / 32), blk, 0, stream>>>(wqkv, wqkvT, 1024, 3072);
    t32cvt_k<<<dim3(1024 / 32, 1024 / 32), blk, 0, stream>>>(wo, woT, 1024, 1024);
    gemm_k<false><<<dim3(3072 / 128, 8192 / 128), blk, 0, stream>>>(xb, wqkvT, qkv, 8192, 3072, 1024);
    vt_k<<<dim3(32, 64), blk, 0, stream>>>(qkv, vt);
    attn_mfma<<<dim3(512), blk, 0, stream>>>(qkv, vt, attn);
    gemm_k<true><<<dim3(1024 / 128, 8192 / 128), blk, 0, stream>>>(attn, woT, out, 8192, 1024, 1024);
}